// Round 4
// baseline (919.268 us; speedup 1.0000x reference)
//
#include <hip/hip_runtime.h>
#include <hip/hip_bf16.h>
#include <stdint.h>

typedef unsigned short u16;
typedef __attribute__((ext_vector_type(8))) short short8;
typedef __attribute__((ext_vector_type(8))) __bf16 bf16x8;
typedef __attribute__((ext_vector_type(4))) float f32x4;

#define DEV static __device__ __forceinline__

DEV float bf2f(u16 u) { uint32_t i = ((uint32_t)u) << 16; float f; __builtin_memcpy(&f, &i, 4); return f; }
DEV u16 f2bf(float f) {
    uint32_t i; __builtin_memcpy(&i, &f, 4);
    uint32_t r = i + 0x7FFFu + ((i >> 16) & 1u);
    return (u16)(r >> 16);
}
DEV float lrelu(float x) { return x >= 0.f ? x : 0.2f * x; }

// ---------------- CSR build ----------------
__global__ void k_count(const int* __restrict__ dst, int* __restrict__ deg, int E) {
    int e = blockIdx.x * 256 + threadIdx.x;
    if (e < E) atomicAdd(&deg[dst[e]], 1);
}

__global__ void k_scanpart(const int* __restrict__ deg, int* __restrict__ bsum, int n, int N) {
    __shared__ int buf[1024];
    int tid = threadIdx.x;
    int i = blockIdx.x * 1024 + tid;
    int v = (i < N) ? deg[i] : 0;
    buf[tid] = v; __syncthreads();
    for (int d = 512; d > 0; d >>= 1) {
        if (tid < d) buf[tid] += buf[tid + d];
        __syncthreads();
    }
    if (tid == 0) bsum[blockIdx.x] = buf[0];
}

__global__ void k_scanbsum(int* bsum, int nb) {
    if (threadIdx.x == 0) {
        int run = 0;
        for (int b = 0; b < nb; ++b) { int t = bsum[b]; bsum[b] = run; run += t; }
    }
}

__global__ void k_scanfinal(const int* __restrict__ deg, const int* __restrict__ bsum,
                            int* __restrict__ off, int* __restrict__ cursor, int n, int N) {
    __shared__ int buf[1024];
    int tid = threadIdx.x;
    int i = blockIdx.x * 1024 + tid;
    int v = (i < N) ? deg[i] : 0;
    buf[tid] = v; __syncthreads();
    for (int d = 1; d < 1024; d <<= 1) {
        int t = (tid >= d) ? buf[tid - d] : 0;
        __syncthreads();
        buf[tid] += t;
        __syncthreads();
    }
    int ex = buf[tid] - v + bsum[blockIdx.x];
    if (i < n) { off[i] = ex; if (i < N) cursor[i] = ex; }
}

__global__ void k_scatter(const int* __restrict__ src, const int* __restrict__ dst,
                          int* __restrict__ cursor, int* __restrict__ srt, int* __restrict__ drt, int E) {
    int e = blockIdx.x * 256 + threadIdx.x;
    if (e < E) {
        int d = dst[e];
        int p = atomicAdd(&cursor[d], 1);
        srt[p] = src[e];
        drt[p] = d;
    }
}

// ---------------- GEMM: out[N,M](bf16) = concat(A1[N,K1],A2[N,K2]) @ W[K,M](f32) ----------------
template<bool A1F>
__global__ __launch_bounds__(256) void gemm_k(const void* __restrict__ A1v, int K1,
                                              const u16* __restrict__ A2, int K2,
                                              const float* __restrict__ W, int M,
                                              u16* __restrict__ out, int N) {
    __shared__ u16 wt[64][328];
    __shared__ u16 As[64][40];
    const int K = K1 + K2;
    const int tid = threadIdx.x;
    const int n0 = blockIdx.x * 64;
    const int cb = blockIdx.y * 64;

    for (int idx = tid; idx < K * 64; idx += 256) {
        int k = idx >> 6, m = idx & 63;
        wt[m][k] = f2bf(W[(size_t)k * M + cb + m]);
    }

    const int wv = tid >> 6, lane = tid & 63;
    const int quad = lane >> 4, r = lane & 15;
    f32x4 acc[4];
#pragma unroll
    for (int ct = 0; ct < 4; ++ct) acc[ct] = (f32x4){0.f, 0.f, 0.f, 0.f};

    const int row = tid >> 2, seg = tid & 3;
    const int gl = n0 + row;

    for (int k0 = 0; k0 < K; k0 += 32) {
        int4 v = {0, 0, 0, 0};
        if (gl < N) {
            if (k0 < K1) {
                if (A1F) {
                    const float* b = (const float*)A1v + (size_t)gl * K1 + k0 + seg * 8;
                    u16 t[8];
#pragma unroll
                    for (int j = 0; j < 8; ++j) t[j] = f2bf(b[j]);
                    __builtin_memcpy(&v, t, 16);
                } else {
                    v = *(const int4*)((const u16*)A1v + (size_t)gl * K1 + k0 + seg * 8);
                }
            } else {
                v = *(const int4*)(A2 + (size_t)gl * K2 + (k0 - K1) + seg * 8);
            }
        }
        *(int4*)&As[row][seg * 8] = v;
        __syncthreads();
        bf16x8 a = __builtin_bit_cast(bf16x8, *(const short8*)&As[wv * 16 + r][quad * 8]);
#pragma unroll
        for (int ct = 0; ct < 4; ++ct) {
            bf16x8 b = __builtin_bit_cast(bf16x8, *(const short8*)&wt[ct * 16 + r][k0 + quad * 8]);
            acc[ct] = __builtin_amdgcn_mfma_f32_16x16x32_bf16(a, b, acc[ct], 0, 0, 0);
        }
        __syncthreads();
    }

#pragma unroll
    for (int ct = 0; ct < 4; ++ct)
#pragma unroll
        for (int rg = 0; rg < 4; ++rg) {
            int grow = n0 + wv * 16 + quad * 4 + rg;
            if (grow < N) out[(size_t)grow * M + cb + ct * 16 + r] = f2bf(acc[ct][rg]);
        }
}

// ---------------- attention coefficients: a_src/a_dst [N,8] fp32 ----------------
__global__ __launch_bounds__(256) void acomp8(const u16* __restrict__ g,
                                              const float* __restrict__ ats, const float* __restrict__ atd,
                                              float* __restrict__ a_src, float* __restrict__ a_dst, int N) {
    int lane = threadIdx.x & 63;
    int node = blockIdx.x * 4 + (threadIdx.x >> 6);
    if (node >= N) return;
    float val = bf2f(g[(size_t)node * 64 + lane]);
    float ps = val * ats[lane];
    float pd = val * atd[lane];
#pragma unroll
    for (int d = 1; d < 8; d <<= 1) { ps += __shfl_xor(ps, d); pd += __shfl_xor(pd, d); }
    if ((lane & 7) == 0) {
        a_src[node * 8 + (lane >> 3)] = ps;
        a_dst[node * 8 + (lane >> 3)] = pd;
    }
}

__global__ __launch_bounds__(256) void acomp16(const u16* __restrict__ g,
                                               const float* __restrict__ ats, const float* __restrict__ atd,
                                               float* __restrict__ a_src, float* __restrict__ a_dst, int N) {
    int lane = threadIdx.x & 63;
    int node = blockIdx.x * 4 + (threadIdx.x >> 6);
    if (node >= N) return;
    float v0 = bf2f(g[(size_t)node * 128 + lane]);
    float v1 = bf2f(g[(size_t)node * 128 + lane + 64]);
    float ps0 = v0 * ats[lane],      pd0 = v0 * atd[lane];
    float ps1 = v1 * ats[lane + 64], pd1 = v1 * atd[lane + 64];
#pragma unroll
    for (int d = 1; d < 16; d <<= 1) {
        ps0 += __shfl_xor(ps0, d); pd0 += __shfl_xor(pd0, d);
        ps1 += __shfl_xor(ps1, d); pd1 += __shfl_xor(pd1, d);
    }
    if ((lane & 15) == 0) {
        int hd = lane >> 4;
        a_src[node * 8 + hd] = ps0;     a_dst[node * 8 + hd] = pd0;
        a_src[node * 8 + hd + 4] = ps1; a_dst[node * 8 + hd + 4] = pd1;
    }
}

// ---------------- edge weights: w16[j][h] = exp(lrelu(a_src[srt[j]][h] + a_dst[drt[j]][h])) ----------------
__global__ __launch_bounds__(256) void k_edgew(const int* __restrict__ srt, const int* __restrict__ drt,
                                               const float* __restrict__ a_src, const float* __restrict__ a_dst,
                                               u16* __restrict__ w16, int E8) {
    int idx = blockIdx.x * 256 + threadIdx.x;
    if (idx >= E8) return;
    int e = idx >> 3, h = idx & 7;
    int s = srt[e], d = drt[e];
    w16[idx] = f2bf(__expf(lrelu(a_src[s * 8 + h] + a_dst[d * 8 + h])));
}

// ---------------- layer 1/2 aggregation: slim gather with precomputed w ----------------
__global__ __launch_bounds__(256) void agg12(const u16* __restrict__ g,
                                             const float* __restrict__ a_src, const float* __restrict__ a_dst,
                                             const int* __restrict__ off, const int* __restrict__ srt,
                                             const u16* __restrict__ w16,
                                             const float* __restrict__ bias, const float* __restrict__ pslope,
                                             u16* __restrict__ hout, int N) {
    int lane = threadIdx.x & 63;
    int node = __builtin_amdgcn_readfirstlane(blockIdx.x * 4 + (threadIdx.x >> 6));
    if (node >= N) return;
    int hd = lane >> 3;
    float ad = a_dst[node * 8 + hd];
    float ws = __expf(lrelu(a_src[node * 8 + hd] + ad));   // self loop
    float s = ws;
    float acc = ws * bf2f(g[(size_t)node * 64 + lane]);
    int jb = off[node], je = off[node + 1];
    int src = (jb < je) ? srt[jb] : 0;                      // scalar load (node uniform)
    for (int j = jb; j < je; ++j) {
        int nsrc = (j + 1 < je) ? srt[j + 1] : 0;           // prefetch next src
        float wv = bf2f(w16[(size_t)j * 8 + hd]);
        float hv = bf2f(g[(size_t)src * 64 + lane]);
        s += wv;
        acc += wv * hv;
        src = nsrc;
    }
    float v = acc / (s + 1e-16f) + bias[lane];
    float p = pslope[0];
    v = v >= 0.f ? v : p * v;
    hout[(size_t)node * 64 + lane] = f2bf(v);
}

// ---------------- layer 3 aggregation + head-mean + bias + log_softmax ----------------
__global__ __launch_bounds__(256) void agg3(const u16* __restrict__ g,
                                            const float* __restrict__ a_src, const float* __restrict__ a_dst,
                                            const int* __restrict__ off, const int* __restrict__ srt,
                                            const u16* __restrict__ w16,
                                            const float* __restrict__ b3, float* __restrict__ out, int N) {
    int lane = threadIdx.x & 63;
    int node = __builtin_amdgcn_readfirstlane(blockIdx.x * 4 + (threadIdx.x >> 6));
    if (node >= N) return;
    int hd0 = lane >> 4, hd1 = hd0 + 4, c = lane & 15;
    float ad0 = a_dst[node * 8 + hd0], ad1 = a_dst[node * 8 + hd1];
    float w0s = __expf(lrelu(a_src[node * 8 + hd0] + ad0));
    float w1s = __expf(lrelu(a_src[node * 8 + hd1] + ad1));
    float s0 = w0s, s1 = w1s;
    float acc0 = w0s * bf2f(g[(size_t)node * 128 + lane]);
    float acc1 = w1s * bf2f(g[(size_t)node * 128 + lane + 64]);
    int jb = off[node], je = off[node + 1];
    int src = (jb < je) ? srt[jb] : 0;
    for (int j = jb; j < je; ++j) {
        int nsrc = (j + 1 < je) ? srt[j + 1] : 0;
        float w0 = bf2f(w16[(size_t)j * 8 + hd0]);
        float w1 = bf2f(w16[(size_t)j * 8 + hd1]);
        float h0 = bf2f(g[(size_t)src * 128 + lane]);
        float h1 = bf2f(g[(size_t)src * 128 + lane + 64]);
        s0 += w0; acc0 += w0 * h0;
        s1 += w1; acc1 += w1 * h1;
        src = nsrc;
    }
    float t = acc0 / (s0 + 1e-16f) + acc1 / (s1 + 1e-16f);
    t += __shfl_xor(t, 16);
    t += __shfl_xor(t, 32);
    float mean = t * 0.125f + b3[c];
    float mx = mean;
#pragma unroll
    for (int d = 1; d < 16; d <<= 1) mx = fmaxf(mx, __shfl_xor(mx, d));
    float ex = __expf(mean - mx), se = ex;
#pragma unroll
    for (int d = 1; d < 16; d <<= 1) se += __shfl_xor(se, d);
    float lsm = mean - mx - __logf(se);
    if (lane < 16) out[(size_t)node * 16 + lane] = lsm;
}

// ---------------- launch ----------------
extern "C" void kernel_launch(void* const* d_in, const int* in_sizes, int n_in,
                              void* d_out, int out_size, void* d_ws, size_t ws_size,
                              hipStream_t stream) {
    (void)n_in; (void)out_size; (void)ws_size;
    const float* x  = (const float*)d_in[0];
    const int* ei   = (const int*)d_in[1];
    const float* W1 = (const float*)d_in[2];
    const float* as1 = (const float*)d_in[3];
    const float* ad1 = (const float*)d_in[4];
    const float* b1  = (const float*)d_in[5];
    const float* W2  = (const float*)d_in[6];
    const float* as2 = (const float*)d_in[7];
    const float* ad2 = (const float*)d_in[8];
    const float* b2  = (const float*)d_in[9];
    const float* W3  = (const float*)d_in[10];
    const float* as3 = (const float*)d_in[11];
    const float* ad3 = (const float*)d_in[12];
    const float* b3  = (const float*)d_in[13];
    const float* p1  = (const float*)d_in[14];
    const float* p2  = (const float*)d_in[15];
    const int N = in_sizes[0] / 256;
    const int E = in_sizes[1] / 2;

    char* ws = (char*)d_ws;
    size_t o = 0;
    auto alloc = [&](size_t bytes) { void* p = ws + o; o = (o + bytes + 255) & ~(size_t)255; return p; };
    int* deg    = (int*)alloc((size_t)N * 4);
    int* off    = (int*)alloc((size_t)(N + 1) * 4);
    int* cursor = (int*)alloc((size_t)N * 4);
    int* bsum   = (int*)alloc(4096);
    int* srt    = (int*)alloc((size_t)E * 4);
    int* drt    = (int*)alloc((size_t)E * 4);
    u16* w16    = (u16*)alloc((size_t)E * 8 * 2);
    u16* g      = (u16*)alloc((size_t)N * 128 * 2);
    float* a_src = (float*)alloc((size_t)N * 8 * 4);
    float* a_dst = (float*)alloc((size_t)N * 8 * 4);
    u16* h1     = (u16*)alloc((size_t)N * 64 * 2);
    u16* h2     = (u16*)alloc((size_t)N * 64 * 2);

    hipMemsetAsync(deg, 0, (size_t)N * 4, stream);
    int eb = (E + 255) / 256;
    k_count<<<eb, 256, 0, stream>>>(ei + E, deg, E);
    int nS = (N + 1 + 1023) / 1024;
    k_scanpart<<<nS, 1024, 0, stream>>>(deg, bsum, N + 1, N);
    k_scanbsum<<<1, 64, 0, stream>>>(bsum, nS);
    k_scanfinal<<<nS, 1024, 0, stream>>>(deg, bsum, off, cursor, N + 1, N);
    k_scatter<<<eb, 256, 0, stream>>>(ei, ei + E, cursor, srt, drt, E);

    int nb64 = (N + 63) / 64;
    int nb4 = (N + 3) / 4;
    int e8b = (E * 8 + 255) / 256;

    // layer 1: x[N,256] @ W1[256,64]
    gemm_k<true><<<dim3(nb64, 1), 256, 0, stream>>>(x, 256, (const u16*)nullptr, 0, W1, 64, g, N);
    acomp8<<<nb4, 256, 0, stream>>>(g, as1, ad1, a_src, a_dst, N);
    k_edgew<<<e8b, 256, 0, stream>>>(srt, drt, a_src, a_dst, w16, E * 8);
    agg12<<<nb4, 256, 0, stream>>>(g, a_src, a_dst, off, srt, w16, b1, p1, h1, N);

    // layer 2: concat(x, h1)[N,320] @ W2[320,64]
    gemm_k<true><<<dim3(nb64, 1), 256, 0, stream>>>(x, 256, h1, 64, W2, 64, g, N);
    acomp8<<<nb4, 256, 0, stream>>>(g, as2, ad2, a_src, a_dst, N);
    k_edgew<<<e8b, 256, 0, stream>>>(srt, drt, a_src, a_dst, w16, E * 8);
    agg12<<<nb4, 256, 0, stream>>>(g, a_src, a_dst, off, srt, w16, b2, p2, h2, N);

    // layer 3: h2[N,64] @ W3[64,128], mean over heads + log_softmax
    gemm_k<false><<<dim3(nb64, 2), 256, 0, stream>>>(h2, 64, (const u16*)nullptr, 0, W3, 128, g, N);
    acomp16<<<nb4, 256, 0, stream>>>(g, as3, ad3, a_src, a_dst, N);
    k_edgew<<<e8b, 256, 0, stream>>>(srt, drt, a_src, a_dst, w16, E * 8);
    agg3<<<nb4, 256, 0, stream>>>(g, a_src, a_dst, off, srt, w16, b3, (float*)d_out, N);
}

// Round 5
// 879.378 us; speedup vs baseline: 1.0454x; 1.0454x over previous
//
#include <hip/hip_runtime.h>
#include <hip/hip_bf16.h>
#include <stdint.h>

typedef unsigned short u16;
typedef __attribute__((ext_vector_type(8))) short short8;
typedef __attribute__((ext_vector_type(8))) __bf16 bf16x8;
typedef __attribute__((ext_vector_type(4))) float f32x4;

#define DEV static __device__ __forceinline__

DEV float bf2f(u16 u) { uint32_t i = ((uint32_t)u) << 16; float f; __builtin_memcpy(&f, &i, 4); return f; }
DEV u16 f2bf(float f) {
    uint32_t i; __builtin_memcpy(&i, &f, 4);
    uint32_t r = i + 0x7FFFu + ((i >> 16) & 1u);
    return (u16)(r >> 16);
}
DEV float lrelu(float x) { return x >= 0.f ? x : 0.2f * x; }

// ---------------- x -> bf16 pre-convert ----------------
__global__ __launch_bounds__(256) void k_cvt(const float* __restrict__ in, u16* __restrict__ out, int n4) {
    int i = blockIdx.x * 256 + threadIdx.x;
    if (i < n4) {
        float4 v = ((const float4*)in)[i];
        ushort4 o;
        o.x = f2bf(v.x); o.y = f2bf(v.y); o.z = f2bf(v.z); o.w = f2bf(v.w);
        ((ushort4*)out)[i] = o;
    }
}

// ---------------- CSR build ----------------
__global__ void k_count(const int* __restrict__ dst, int* __restrict__ deg, int E) {
    int e = blockIdx.x * 256 + threadIdx.x;
    if (e < E) atomicAdd(&deg[dst[e]], 1);
}

__global__ void k_scanpart(const int* __restrict__ deg, int* __restrict__ bsum, int n, int N) {
    __shared__ int buf[1024];
    int tid = threadIdx.x;
    int i = blockIdx.x * 1024 + tid;
    int v = (i < N) ? deg[i] : 0;
    buf[tid] = v; __syncthreads();
    for (int d = 512; d > 0; d >>= 1) {
        if (tid < d) buf[tid] += buf[tid + d];
        __syncthreads();
    }
    if (tid == 0) bsum[blockIdx.x] = buf[0];
}

__global__ void k_scanbsum(int* bsum, int nb) {
    if (threadIdx.x == 0) {
        int run = 0;
        for (int b = 0; b < nb; ++b) { int t = bsum[b]; bsum[b] = run; run += t; }
    }
}

__global__ void k_scanfinal(const int* __restrict__ deg, const int* __restrict__ bsum,
                            int* __restrict__ off, int* __restrict__ cursor, int n, int N) {
    __shared__ int buf[1024];
    int tid = threadIdx.x;
    int i = blockIdx.x * 1024 + tid;
    int v = (i < N) ? deg[i] : 0;
    buf[tid] = v; __syncthreads();
    for (int d = 1; d < 1024; d <<= 1) {
        int t = (tid >= d) ? buf[tid - d] : 0;
        __syncthreads();
        buf[tid] += t;
        __syncthreads();
    }
    int ex = buf[tid] - v + bsum[blockIdx.x];
    if (i < n) { off[i] = ex; if (i < N) cursor[i] = ex; }
}

__global__ void k_scatter(const int* __restrict__ src, const int* __restrict__ dst,
                          int* __restrict__ cursor, int* __restrict__ srt, int E) {
    int e = blockIdx.x * 256 + threadIdx.x;
    if (e < E) { int p = atomicAdd(&cursor[dst[e]], 1); srt[p] = src[e]; }
}

// ---------------- GEMM: out[N,M](bf16) = concat(A1[N,K1],A2[N,K2])(bf16) @ W[K,M](f32) ----------------
__global__ __launch_bounds__(256) void gemm_k(const u16* __restrict__ A1, int K1,
                                              const u16* __restrict__ A2, int K2,
                                              const float* __restrict__ W, int M,
                                              u16* __restrict__ out, int N) {
    __shared__ u16 wt[64][328];
    __shared__ u16 As[64][40];
    const int K = K1 + K2;
    const int tid = threadIdx.x;
    const int n0 = blockIdx.x * 64;
    const int cb = blockIdx.y * 64;

    for (int idx = tid; idx < K * 64; idx += 256) {
        int k = idx >> 6, m = idx & 63;
        wt[m][k] = f2bf(W[(size_t)k * M + cb + m]);
    }

    const int wv = tid >> 6, lane = tid & 63;
    const int quad = lane >> 4, r = lane & 15;
    f32x4 acc[4];
#pragma unroll
    for (int ct = 0; ct < 4; ++ct) acc[ct] = (f32x4){0.f, 0.f, 0.f, 0.f};

    const int row = tid >> 2, seg = tid & 3;
    const int gl = n0 + row;

    for (int k0 = 0; k0 < K; k0 += 32) {
        int4 v = {0, 0, 0, 0};
        if (gl < N) {
            const u16* base = (k0 < K1) ? (A1 + (size_t)gl * K1 + k0)
                                        : (A2 + (size_t)gl * K2 + (k0 - K1));
            v = *(const int4*)(base + seg * 8);
        }
        *(int4*)&As[row][seg * 8] = v;
        __syncthreads();
        bf16x8 a = __builtin_bit_cast(bf16x8, *(const short8*)&As[wv * 16 + r][quad * 8]);
#pragma unroll
        for (int ct = 0; ct < 4; ++ct) {
            bf16x8 b = __builtin_bit_cast(bf16x8, *(const short8*)&wt[ct * 16 + r][k0 + quad * 8]);
            acc[ct] = __builtin_amdgcn_mfma_f32_16x16x32_bf16(a, b, acc[ct], 0, 0, 0);
        }
        __syncthreads();
    }

#pragma unroll
    for (int ct = 0; ct < 4; ++ct)
#pragma unroll
        for (int rg = 0; rg < 4; ++rg) {
            int grow = n0 + wv * 16 + quad * 4 + rg;
            if (grow < N) out[(size_t)grow * M + cb + ct * 16 + r] = f2bf(acc[ct][rg]);
        }
}

// ---------------- attention coefficients: a_src/a_dst [N,8] fp32 ----------------
__global__ __launch_bounds__(256) void acomp8(const u16* __restrict__ g,
                                              const float* __restrict__ ats, const float* __restrict__ atd,
                                              float* __restrict__ a_src, float* __restrict__ a_dst, int N) {
    int lane = threadIdx.x & 63;
    int node = blockIdx.x * 4 + (threadIdx.x >> 6);
    if (node >= N) return;
    float val = bf2f(g[(size_t)node * 64 + lane]);
    float ps = val * ats[lane];
    float pd = val * atd[lane];
#pragma unroll
    for (int d = 1; d < 8; d <<= 1) { ps += __shfl_xor(ps, d); pd += __shfl_xor(pd, d); }
    if ((lane & 7) == 0) {
        a_src[node * 8 + (lane >> 3)] = ps;
        a_dst[node * 8 + (lane >> 3)] = pd;
    }
}

__global__ __launch_bounds__(256) void acomp16(const u16* __restrict__ g,
                                               const float* __restrict__ ats, const float* __restrict__ atd,
                                               float* __restrict__ a_src, float* __restrict__ a_dst, int N) {
    int lane = threadIdx.x & 63;
    int node = blockIdx.x * 4 + (threadIdx.x >> 6);
    if (node >= N) return;
    float v0 = bf2f(g[(size_t)node * 128 + lane]);
    float v1 = bf2f(g[(size_t)node * 128 + lane + 64]);
    float ps0 = v0 * ats[lane],      pd0 = v0 * atd[lane];
    float ps1 = v1 * ats[lane + 64], pd1 = v1 * atd[lane + 64];
#pragma unroll
    for (int d = 1; d < 16; d <<= 1) {
        ps0 += __shfl_xor(ps0, d); pd0 += __shfl_xor(pd0, d);
        ps1 += __shfl_xor(ps1, d); pd1 += __shfl_xor(pd1, d);
    }
    if ((lane & 15) == 0) {
        int hd = lane >> 4;
        a_src[node * 8 + hd] = ps0;     a_dst[node * 8 + hd] = pd0;
        a_src[node * 8 + hd + 4] = ps1; a_dst[node * 8 + hd + 4] = pd1;
    }
}

// ---------------- layer 1/2 aggregation: chunk-of-8 fused weights + gather ----------------
__global__ __launch_bounds__(256) void agg12(const u16* __restrict__ g,
                                             const float* __restrict__ a_src, const float* __restrict__ a_dst,
                                             const int* __restrict__ off, const int* __restrict__ srt,
                                             const float* __restrict__ bias, const float* __restrict__ pslope,
                                             u16* __restrict__ hout, int N) {
    int lane = threadIdx.x & 63;
    int node = blockIdx.x * 4 + (threadIdx.x >> 6);
    if (node >= N) return;
    int hd = lane >> 3;   // head for accumulation layout (channel = lane)
    int hw = lane & 7;    // head for weight-compute layout (edge = lane>>3)
    float ad_acc = a_dst[node * 8 + hd];
    float ad_w   = a_dst[node * 8 + hw];
    float ws = __expf(lrelu(a_src[node * 8 + hd] + ad_acc));   // self loop
    float s = ws;
    float acc = ws * bf2f(g[(size_t)node * 64 + lane]);
    int jb = off[node], je = off[node + 1];
    for (int j0 = jb; j0 < je; j0 += 8) {
        int cnt = je - j0; if (cnt > 8) cnt = 8;
        int jj = j0 + (lane >> 3);
        int idx = (jj < je) ? srt[jj] : 0;
        float w = __expf(lrelu(a_src[idx * 8 + hw] + ad_w));
#pragma unroll
        for (int t = 0; t < 8; ++t) {
            if (t >= cnt) break;
            int srcv = __shfl(idx, t * 8);
            float wv = __shfl(w, t * 8 + hd);
            float hv = bf2f(g[(size_t)srcv * 64 + lane]);
            s += wv;
            acc += wv * hv;
        }
    }
    float v = acc / (s + 1e-16f) + bias[lane];
    float p = pslope[0];
    v = v >= 0.f ? v : p * v;
    hout[(size_t)node * 64 + lane] = f2bf(v);
}

// ---------------- layer 3 aggregation + head-mean + bias + log_softmax ----------------
__global__ __launch_bounds__(256) void agg3(const u16* __restrict__ g,
                                            const float* __restrict__ a_src, const float* __restrict__ a_dst,
                                            const int* __restrict__ off, const int* __restrict__ srt,
                                            const float* __restrict__ b3, float* __restrict__ out, int N) {
    int lane = threadIdx.x & 63;
    int node = blockIdx.x * 4 + (threadIdx.x >> 6);
    if (node >= N) return;
    int hd0 = lane >> 4, hd1 = hd0 + 4, c = lane & 15;
    int hw = lane & 7;
    float ad0 = a_dst[node * 8 + hd0], ad1 = a_dst[node * 8 + hd1];
    float ad_w = a_dst[node * 8 + hw];
    float w0s = __expf(lrelu(a_src[node * 8 + hd0] + ad0));
    float w1s = __expf(lrelu(a_src[node * 8 + hd1] + ad1));
    float s0 = w0s, s1 = w1s;
    float acc0 = w0s * bf2f(g[(size_t)node * 128 + lane]);
    float acc1 = w1s * bf2f(g[(size_t)node * 128 + lane + 64]);
    int jb = off[node], je = off[node + 1];
    for (int j0 = jb; j0 < je; j0 += 8) {
        int cnt = je - j0; if (cnt > 8) cnt = 8;
        int jj = j0 + (lane >> 3);
        int idx = (jj < je) ? srt[jj] : 0;
        float w = __expf(lrelu(a_src[idx * 8 + hw] + ad_w));
#pragma unroll
        for (int t = 0; t < 8; ++t) {
            if (t >= cnt) break;
            int srcv = __shfl(idx, t * 8);
            float wv0 = __shfl(w, t * 8 + hd0);
            float wv1 = __shfl(w, t * 8 + hd1);
            float h0 = bf2f(g[(size_t)srcv * 128 + lane]);
            float h1 = bf2f(g[(size_t)srcv * 128 + lane + 64]);
            s0 += wv0; acc0 += wv0 * h0;
            s1 += wv1; acc1 += wv1 * h1;
        }
    }
    float t = acc0 / (s0 + 1e-16f) + acc1 / (s1 + 1e-16f);
    t += __shfl_xor(t, 16);
    t += __shfl_xor(t, 32);
    float mean = t * 0.125f + b3[c];
    float mx = mean;
#pragma unroll
    for (int d = 1; d < 16; d <<= 1) mx = fmaxf(mx, __shfl_xor(mx, d));
    float ex = __expf(mean - mx), se = ex;
#pragma unroll
    for (int d = 1; d < 16; d <<= 1) se += __shfl_xor(se, d);
    float lsm = mean - mx - __logf(se);
    if (lane < 16) out[(size_t)node * 16 + lane] = lsm;
}

// ---------------- launch ----------------
extern "C" void kernel_launch(void* const* d_in, const int* in_sizes, int n_in,
                              void* d_out, int out_size, void* d_ws, size_t ws_size,
                              hipStream_t stream) {
    (void)n_in; (void)out_size; (void)ws_size;
    const float* x  = (const float*)d_in[0];
    const int* ei   = (const int*)d_in[1];
    const float* W1 = (const float*)d_in[2];
    const float* as1 = (const float*)d_in[3];
    const float* ad1 = (const float*)d_in[4];
    const float* b1  = (const float*)d_in[5];
    const float* W2  = (const float*)d_in[6];
    const float* as2 = (const float*)d_in[7];
    const float* ad2 = (const float*)d_in[8];
    const float* b2  = (const float*)d_in[9];
    const float* W3  = (const float*)d_in[10];
    const float* as3 = (const float*)d_in[11];
    const float* ad3 = (const float*)d_in[12];
    const float* b3  = (const float*)d_in[13];
    const float* p1  = (const float*)d_in[14];
    const float* p2  = (const float*)d_in[15];
    const int N = in_sizes[0] / 256;
    const int E = in_sizes[1] / 2;

    char* ws = (char*)d_ws;
    size_t o = 0;
    auto alloc = [&](size_t bytes) { void* p = ws + o; o = (o + bytes + 255) & ~(size_t)255; return p; };
    int* deg    = (int*)alloc((size_t)N * 4);
    int* off    = (int*)alloc((size_t)(N + 1) * 4);
    int* cursor = (int*)alloc((size_t)N * 4);
    int* bsum   = (int*)alloc(4096);
    int* srt    = (int*)alloc((size_t)E * 4);
    u16* xb     = (u16*)alloc((size_t)N * 256 * 2);
    u16* g      = (u16*)alloc((size_t)N * 128 * 2);
    float* a_src = (float*)alloc((size_t)N * 8 * 4);
    float* a_dst = (float*)alloc((size_t)N * 8 * 4);
    u16* h1     = (u16*)alloc((size_t)N * 64 * 2);
    u16* h2     = (u16*)alloc((size_t)N * 64 * 2);

    hipMemsetAsync(deg, 0, (size_t)N * 4, stream);
    int n4 = N * 256 / 4;
    k_cvt<<<(n4 + 255) / 256, 256, 0, stream>>>(x, xb, n4);
    int eb = (E + 255) / 256;
    k_count<<<eb, 256, 0, stream>>>(ei + E, deg, E);
    int nS = (N + 1 + 1023) / 1024;
    k_scanpart<<<nS, 1024, 0, stream>>>(deg, bsum, N + 1, N);
    k_scanbsum<<<1, 64, 0, stream>>>(bsum, nS);
    k_scanfinal<<<nS, 1024, 0, stream>>>(deg, bsum, off, cursor, N + 1, N);
    k_scatter<<<eb, 256, 0, stream>>>(ei, ei + E, cursor, srt, E);

    int nb64 = (N + 63) / 64;
    int nb4 = (N + 3) / 4;

    // layer 1: x[N,256] @ W1[256,64]
    gemm_k<<<dim3(nb64, 1), 256, 0, stream>>>(xb, 256, (const u16*)nullptr, 0, W1, 64, g, N);
    acomp8<<<nb4, 256, 0, stream>>>(g, as1, ad1, a_src, a_dst, N);
    agg12<<<nb4, 256, 0, stream>>>(g, a_src, a_dst, off, srt, b1, p1, h1, N);

    // layer 2: concat(x, h1)[N,320] @ W2[320,64]
    gemm_k<<<dim3(nb64, 1), 256, 0, stream>>>(xb, 256, h1, 64, W2, 64, g, N);
    acomp8<<<nb4, 256, 0, stream>>>(g, as2, ad2, a_src, a_dst, N);
    agg12<<<nb4, 256, 0, stream>>>(g, a_src, a_dst, off, srt, b2, p2, h2, N);

    // layer 3: h2[N,64] @ W3[64,128], mean over heads + log_softmax
    gemm_k<<<dim3(nb64, 2), 256, 0, stream>>>(h2, 64, (const u16*)nullptr, 0, W3, 128, g, N);
    acomp16<<<nb4, 256, 0, stream>>>(g, as3, ad3, a_src, a_dst, N);
    agg3<<<nb4, 256, 0, stream>>>(g, a_src, a_dst, off, srt, b3, (float*)d_out, N);
}